// Round 3
// baseline (907.038 us; speedup 1.0000x reference)
//
#include <hip/hip_runtime.h>
#include <hip/hip_bf16.h>
#include <math.h>

#define N_NODES 100000
#define N_EDGES 1600000
#define FIN 14
#define H 64
#define NB 105
#define S_CNT 10000
#define SCAN_BLOCKS 391   // ceil(100000/256)
#define LGJ 224           // 105 (head b) | 7 pad | 105 (head s @112) | 7 pad
#define M_TILE 16

// ---------------- degree histogram (edges only; +1 self-loop added in dis) ----
__global__ __launch_bounds__(256) void deg_kernel(const int* __restrict__ dst,
                                                  int* __restrict__ deg) {
    int e = blockIdx.x * 256 + threadIdx.x;   // grid exact: 6250*256 = 1.6M
    atomicAdd(&deg[dst[e]], 1);
}

__global__ __launch_bounds__(256) void stem_kernel(const int* __restrict__ idx,
                                                   float* __restrict__ stem01) {
    int i = blockIdx.x * 256 + threadIdx.x;
    if (i < S_CNT) stem01[idx[i]] = 1.0f;
}

__global__ __launch_bounds__(256) void dis_kernel(const int* __restrict__ deg,
                                                  float* __restrict__ dis) {
    int i = blockIdx.x * 256 + threadIdx.x;
    if (i < N_NODES) dis[i] = rsqrtf((float)deg[i] + 1.0f);  // +1 self loop
}

// ---------------- CSR build: scan deg -> rowptr, scatter src by dst ----------
__global__ __launch_bounds__(256) void scan1_kernel(const int* __restrict__ deg,
                                                    int* __restrict__ rowptr,
                                                    int* __restrict__ bsum) {
    __shared__ int s[256];
    int t = threadIdx.x;
    int i = blockIdx.x * 256 + t;
    int v = (i < N_NODES) ? deg[i] : 0;
    s[t] = v;
    __syncthreads();
#pragma unroll
    for (int o = 1; o < 256; o <<= 1) {
        int x = (t >= o) ? s[t - o] : 0;
        __syncthreads();
        s[t] += x;
        __syncthreads();
    }
    if (i < N_NODES) rowptr[i + 1] = s[t];
    if (t == 255) bsum[blockIdx.x] = s[255];
}

__global__ __launch_bounds__(512) void scan2_kernel(const int* __restrict__ bsum,
                                                    int* __restrict__ boff) {
    __shared__ int s[512];
    int t = threadIdx.x;
    int v = (t < SCAN_BLOCKS) ? bsum[t] : 0;
    s[t] = v;
    __syncthreads();
#pragma unroll
    for (int o = 1; o < 512; o <<= 1) {
        int x = (t >= o) ? s[t - o] : 0;
        __syncthreads();
        s[t] += x;
        __syncthreads();
    }
    if (t < SCAN_BLOCKS) boff[t] = s[t] - v;   // exclusive
}

__global__ __launch_bounds__(256) void scan3_kernel(const int* __restrict__ boff,
                                                    int* __restrict__ rowptr,
                                                    int* __restrict__ cursor) {
    int t = threadIdx.x;
    int i = blockIdx.x * 256 + t;
    if (i < N_NODES) {
        int val = rowptr[i + 1] + boff[blockIdx.x];
        rowptr[i + 1] = val;
        if (i + 1 < N_NODES) cursor[i + 1] = val;
    }
    if (i == 0) { rowptr[0] = 0; cursor[0] = 0; }
}

__global__ __launch_bounds__(256) void scatter_kernel(const int* __restrict__ src,
                                                      const int* __restrict__ dst,
                                                      int* __restrict__ cursor,
                                                      int* __restrict__ col) {
    int e = blockIdx.x * 256 + threadIdx.x;   // grid exact
    int d = dst[e];
    int pos = atomicAdd(&cursor[d], 1);
    col[pos] = src[e];
}

// ---------------- xws1 = ([x, stem] @ W1) * dis  (K=15) ----------------
__global__ __launch_bounds__(256) void xw1_kernel(const float* __restrict__ x,
                                                  const float* __restrict__ stem01,
                                                  const float* __restrict__ dis,
                                                  const float* __restrict__ W1,
                                                  float* __restrict__ xws) {
    __shared__ __align__(16) float W1s[15 * 64];
    __shared__ __align__(16) float xs[4][16];
    int tid = threadIdx.x;
    for (int i = tid; i < 960; i += 256) W1s[i] = W1[i];
    int n0 = blockIdx.x * 4;                     // grid exact: 25000*4 = 100000
    if (tid < 60) {
        int r = tid / 15, k = tid % 15;
        int n = n0 + r;
        xs[r][k] = (k < FIN) ? x[n * FIN + k] : stem01[n];
    }
    __syncthreads();
    int r = tid >> 6, f = tid & 63;
    float acc = 0.f;
#pragma unroll
    for (int k = 0; k < 15; k++) acc += xs[r][k] * W1s[k * 64 + f];
    xws[(n0 + r) * 64 + f] = acc * dis[n0 + r];
}

// ---------------- CSR aggregation + fused epilogue ----------------
// acc = xws[node] + sum_{s in N(node)} xws[s];  h = relu(dis[node]*acc + b)*drop
__global__ __launch_bounds__(256) void agg_csr_kernel(const float* __restrict__ xws,
                                                      const int* __restrict__ rowptr,
                                                      const int* __restrict__ col,
                                                      const float* __restrict__ dis,
                                                      const float* __restrict__ bias,
                                                      const float* __restrict__ drop,
                                                      float* __restrict__ hout) {
    int node = (blockIdx.x * 256 + threadIdx.x) >> 6;  // grid exact: 25000*4
    int f = threadIdx.x & 63;
    int beg = rowptr[node], end = rowptr[node + 1];
    float acc0 = xws[node * 64 + f];   // self loop (already * dis[node])
    float acc1 = 0.f, acc2 = 0.f, acc3 = 0.f;
    int j = beg;
    for (; j + 4 <= end; j += 4) {
        int s0 = col[j], s1 = col[j + 1], s2 = col[j + 2], s3 = col[j + 3];
        acc0 += xws[s0 * 64 + f];
        acc1 += xws[s1 * 64 + f];
        acc2 += xws[s2 * 64 + f];
        acc3 += xws[s3 * 64 + f];
    }
    for (; j < end; j++) acc0 += xws[col[j] * 64 + f];
    float acc = (acc0 + acc1) + (acc2 + acc3);
    float r = fmaxf(fmaf(dis[node], acc, bias[f]), 0.f) * drop[node * 64 + f];
    hout[node * 64 + f] = r;
}

// ---------------- xws2 = (h1 @ W2) * dis  (64x64), in-place safe -------------
__global__ __launch_bounds__(256) void xw2_kernel(const float* __restrict__ h,
                                                  const float* __restrict__ dis,
                                                  const float* __restrict__ W2,
                                                  float* __restrict__ xws) {
    __shared__ __align__(16) float W2s[64 * 64];     // 16 KB
    __shared__ __align__(16) float hsT[64 * 68];     // k-major, pad 68: 17 KB
    int tid = threadIdx.x;
    for (int i = tid; i < 4096; i += 256) W2s[i] = W2[i];
    int n0 = blockIdx.x * 64;                        // grid 1563, tail guarded
    for (int i = tid; i < 4096; i += 256) {
        int m = i >> 6, k = i & 63;
        int n = n0 + m;
        hsT[k * 68 + m] = (n < N_NODES) ? h[n * 64 + k] : 0.f;
    }
    __syncthreads();
    int fg = tid & 15, mg = tid >> 4;
    int f0 = fg * 4, m0 = mg * 4;
    float acc[4][4];
#pragma unroll
    for (int i = 0; i < 4; i++)
#pragma unroll
        for (int j = 0; j < 4; j++) acc[i][j] = 0.f;
    for (int k = 0; k < 64; k++) {
        float4 w = *(const float4*)&W2s[k * 64 + f0];
        float4 hv = *(const float4*)&hsT[k * 68 + m0];
        float hh[4] = {hv.x, hv.y, hv.z, hv.w};
#pragma unroll
        for (int i = 0; i < 4; i++) {
            acc[i][0] += hh[i] * w.x;
            acc[i][1] += hh[i] * w.y;
            acc[i][2] += hh[i] * w.z;
            acc[i][3] += hh[i] * w.w;
        }
    }
#pragma unroll
    for (int i = 0; i < 4; i++) {
        int n = n0 + m0 + i;
        if (n < N_NODES) {
            float ds = dis[n];
            float4 r = make_float4(acc[i][0] * ds, acc[i][1] * ds,
                                   acc[i][2] * ds, acc[i][3] * ds);
            *(float4*)&xws[n * 64 + f0] = r;
        }
    }
}

// ---------------- fused head: logits + bias + gumbel softmax ----------------
// Phase 1: C[16,224] = h2[16,64] @ Wall[64,224] (Wall = [Wb | pad | Ws | pad])
//   thread (tj,tm) = (tid%56, tid/56), tid<224: owns j = 4tj..4tj+3, m = 4tm..4tm+3
//   Wall reads: lane-contiguous b128 (conflict-free); hT reads: wave-broadcast.
// Phase 2: logits -> LDS (reusing Wall region)
// Phase 3: 32-lane groups per (m, head): online softmax + all global writes.
__global__ __launch_bounds__(256) void head_kernel(const float* __restrict__ h2,
                                                   const float* __restrict__ Wb,
                                                   const float* __restrict__ bb,
                                                   const float* __restrict__ Ws,
                                                   const float* __restrict__ bs,
                                                   const float* __restrict__ gb,
                                                   const float* __restrict__ gs,
                                                   float* __restrict__ out) {
    __shared__ __align__(16) float smem[64 * LGJ + 64 * 20];  // 62464 B
    float* Wall = smem;            // [64][224], reused as Lg[16][224] in phase 2/3
    float* hT   = smem + 64 * LGJ; // [64][20] (pad 20 keeps b128 aligned, ~2-way wr)
    int tid = threadIdx.x;
    int n0 = blockIdx.x * M_TILE;  // grid exact: 6250*16 = 100000

    // stage W (L2-resident source)
    for (int i = tid; i < 64 * LGJ; i += 256) {
        int k = i / LGJ, j = i - k * LGJ;
        float w = 0.f;
        if (j < NB) w = Wb[k * NB + j];
        else if (j >= 112 && j < 112 + NB) w = Ws[k * NB + (j - 112)];
        Wall[i] = w;
    }
    // stage h2 tile, k-major
    {
        int m = tid >> 4, kq = tid & 15;
        float4 hv = *(const float4*)&h2[(size_t)(n0 + m) * 64 + kq * 4];
        hT[(kq * 4 + 0) * 20 + m] = hv.x;
        hT[(kq * 4 + 1) * 20 + m] = hv.y;
        hT[(kq * 4 + 2) * 20 + m] = hv.z;
        hT[(kq * 4 + 3) * 20 + m] = hv.w;
    }
    __syncthreads();

    int tj = tid % 56, tm = tid / 56;
    bool active = tid < 224;
    float acc[4][4];
#pragma unroll
    for (int a = 0; a < 4; a++)
#pragma unroll
        for (int b = 0; b < 4; b++) acc[a][b] = 0.f;
    if (active) {
        for (int k = 0; k < 64; k++) {
            float4 w = *(const float4*)&Wall[k * LGJ + tj * 4];
            float4 hv = *(const float4*)&hT[k * 20 + tm * 4];
            float wv[4] = {w.x, w.y, w.z, w.w};
            float hh[4] = {hv.x, hv.y, hv.z, hv.w};
#pragma unroll
            for (int a = 0; a < 4; a++)
#pragma unroll
                for (int b = 0; b < 4; b++) acc[a][b] += wv[a] * hh[b];
        }
    }
    __syncthreads();
    if (active) {
#pragma unroll
        for (int b = 0; b < 4; b++) {
            float4 v = make_float4(acc[0][b], acc[1][b], acc[2][b], acc[3][b]);
            *(float4*)&Wall[(tm * 4 + b) * LGJ + tj * 4] = v;  // Lg[m][j]
        }
    }
    __syncthreads();

    // softmax: 8 groups of 32 lanes, 4 passes -> 32 (m, head) pairs
    int lane = tid & 31;
    int grp = tid >> 5;
    for (int pass = 0; pass < 4; pass++) {
        int p = grp + 8 * pass;
        int m = p >> 1, head = p & 1;
        int n = n0 + m;
        const float* bias = head ? bs : bb;
        const float* gum = head ? gs : gb;
        int jbase = head ? 112 : 0;
        float lg[4], z[4], e[4];
        float mx = -INFINITY;
#pragma unroll
        for (int i = 0; i < 4; i++) {
            int c = lane + 32 * i;
            if (c < NB) {
                lg[i] = Wall[m * LGJ + jbase + c] + bias[c];
                z[i] = lg[i] + gum[(size_t)n * NB + c];
            } else {
                lg[i] = 0.f;
                z[i] = -INFINITY;
            }
            mx = fmaxf(mx, z[i]);
        }
#pragma unroll
        for (int off = 16; off; off >>= 1) mx = fmaxf(mx, __shfl_xor(mx, off));
        float s = 0.f;
#pragma unroll
        for (int i = 0; i < 4; i++) {
            int c = lane + 32 * i;
            e[i] = (c < NB) ? __expf(z[i] - mx) : 0.f;
            s += e[i];
        }
#pragma unroll
        for (int off = 16; off; off >>= 1) s += __shfl_xor(s, off);
        float inv = 1.f / s;
        float* lo = out + (size_t)head * (N_NODES * NB) + (size_t)n * NB;
        float* so = out + (size_t)(2 + head) * (N_NODES * NB) + (size_t)n * NB;
#pragma unroll
        for (int i = 0; i < 4; i++) {
            int c = lane + 32 * i;
            if (c < NB) {
                lo[c] = lg[i];
                so[c] = e[i] * inv;
            }
        }
    }
}

extern "C" void kernel_launch(void* const* d_in, const int* in_sizes, int n_in,
                              void* d_out, int out_size, void* d_ws, size_t ws_size,
                              hipStream_t stream) {
    const float* x     = (const float*)d_in[0];
    const float* W1    = (const float*)d_in[1];
    const float* b1    = (const float*)d_in[2];
    const float* W2    = (const float*)d_in[3];
    const float* b2    = (const float*)d_in[4];
    const float* Wb    = (const float*)d_in[5];
    const float* bb    = (const float*)d_in[6];
    const float* Ws    = (const float*)d_in[7];
    const float* bs    = (const float*)d_in[8];
    const float* drop1 = (const float*)d_in[9];
    const float* drop2 = (const float*)d_in[10];
    const float* gb    = (const float*)d_in[11];
    const float* gs    = (const float*)d_in[12];
    const int* edge    = (const int*)d_in[13];   // [2, E]
    const int* stem    = (const int*)d_in[14];   // [S]
    float* out = (float*)d_out;

    // workspace (4-byte elems):
    // A[N*64] (xws1, then h2) | B[N*64] (h1, then xws2 in-place) |
    // dis[N] | stem01[N] | deg[N] | rowptr[N+1] | cursor[N] |
    // bsum[391] | boff[391] | col[E]
    float* A      = (float*)d_ws;
    float* B      = A + (size_t)N_NODES * 64;
    float* dis    = B + (size_t)N_NODES * 64;
    float* stem01 = dis + N_NODES;
    int*   deg    = (int*)(stem01 + N_NODES);
    int*   rowptr = deg + N_NODES;
    int*   cursor = rowptr + (N_NODES + 1);
    int*   bsum   = cursor + N_NODES;
    int*   boff   = bsum + SCAN_BLOCKS;
    int*   col    = boff + SCAN_BLOCKS;

    const int* esrc = edge;
    const int* edst = edge + N_EDGES;

    hipMemsetAsync(deg, 0, N_NODES * sizeof(int), stream);
    hipMemsetAsync(stem01, 0, N_NODES * sizeof(float), stream);

    deg_kernel<<<N_EDGES / 256, 256, 0, stream>>>(edst, deg);
    stem_kernel<<<(S_CNT + 255) / 256, 256, 0, stream>>>(stem, stem01);
    dis_kernel<<<SCAN_BLOCKS, 256, 0, stream>>>(deg, dis);

    // CSR build
    scan1_kernel<<<SCAN_BLOCKS, 256, 0, stream>>>(deg, rowptr, bsum);
    scan2_kernel<<<1, 512, 0, stream>>>(bsum, boff);
    scan3_kernel<<<SCAN_BLOCKS, 256, 0, stream>>>(boff, rowptr, cursor);
    scatter_kernel<<<N_EDGES / 256, 256, 0, stream>>>(esrc, edst, cursor, col);

    // layer 1: xws1 -> A; h1 -> B
    xw1_kernel<<<N_NODES / 4, 256, 0, stream>>>(x, stem01, dis, W1, A);
    agg_csr_kernel<<<(N_NODES * 64) / 256, 256, 0, stream>>>(A, rowptr, col, dis, b1, drop1, B);

    // layer 2: xws2 -> B (in-place over h1); h2 -> A
    xw2_kernel<<<(N_NODES + 63) / 64, 256, 0, stream>>>(B, dis, W2, B);
    agg_csr_kernel<<<(N_NODES * 64) / 256, 256, 0, stream>>>(B, rowptr, col, dis, b2, drop2, A);

    // fused heads: logits + gumbel softmax -> all 4 output sections
    head_kernel<<<N_NODES / M_TILE, 256, 0, stream>>>(A, Wb, bb, Ws, bs, gb, gs, out);
}

// Round 4
// 767.040 us; speedup vs baseline: 1.1825x; 1.1825x over previous
//
#include <hip/hip_runtime.h>
#include <hip/hip_bf16.h>
#include <math.h>

#define N_NODES 100000
#define N_EDGES 1600000
#define FIN 14
#define H 64
#define NB 105
#define S_CNT 10000
#define SCAN_BLOCKS 391   // ceil(100000/256)
#define LGJ 224           // 105 (head b) | 7 pad | 105 (head s @112) | 7 pad
#define HM 64             // nodes per head block
#define LGS 232           // Lg row stride (fp32)

// ---------------- degree histogram (edges only; +1 self-loop added in dis) ----
__global__ __launch_bounds__(256) void deg_kernel(const int* __restrict__ dst,
                                                  int* __restrict__ deg) {
    int e = blockIdx.x * 256 + threadIdx.x;   // grid exact: 6250*256 = 1.6M
    atomicAdd(&deg[dst[e]], 1);
}

__global__ __launch_bounds__(256) void stem_kernel(const int* __restrict__ idx,
                                                   float* __restrict__ stem01) {
    int i = blockIdx.x * 256 + threadIdx.x;
    if (i < S_CNT) stem01[idx[i]] = 1.0f;
}

__global__ __launch_bounds__(256) void dis_kernel(const int* __restrict__ deg,
                                                  float* __restrict__ dis) {
    int i = blockIdx.x * 256 + threadIdx.x;
    if (i < N_NODES) dis[i] = rsqrtf((float)deg[i] + 1.0f);  // +1 self loop
}

// ---------------- CSR build: scan deg -> rowptr, scatter src by dst ----------
__global__ __launch_bounds__(256) void scan1_kernel(const int* __restrict__ deg,
                                                    int* __restrict__ rowptr,
                                                    int* __restrict__ bsum) {
    __shared__ int s[256];
    int t = threadIdx.x;
    int i = blockIdx.x * 256 + t;
    int v = (i < N_NODES) ? deg[i] : 0;
    s[t] = v;
    __syncthreads();
#pragma unroll
    for (int o = 1; o < 256; o <<= 1) {
        int x = (t >= o) ? s[t - o] : 0;
        __syncthreads();
        s[t] += x;
        __syncthreads();
    }
    if (i < N_NODES) rowptr[i + 1] = s[t];
    if (t == 255) bsum[blockIdx.x] = s[255];
}

__global__ __launch_bounds__(512) void scan2_kernel(const int* __restrict__ bsum,
                                                    int* __restrict__ boff) {
    __shared__ int s[512];
    int t = threadIdx.x;
    int v = (t < SCAN_BLOCKS) ? bsum[t] : 0;
    s[t] = v;
    __syncthreads();
#pragma unroll
    for (int o = 1; o < 512; o <<= 1) {
        int x = (t >= o) ? s[t - o] : 0;
        __syncthreads();
        s[t] += x;
        __syncthreads();
    }
    if (t < SCAN_BLOCKS) boff[t] = s[t] - v;   // exclusive
}

__global__ __launch_bounds__(256) void scan3_kernel(const int* __restrict__ boff,
                                                    int* __restrict__ rowptr,
                                                    int* __restrict__ cursor) {
    int t = threadIdx.x;
    int i = blockIdx.x * 256 + t;
    if (i < N_NODES) {
        int val = rowptr[i + 1] + boff[blockIdx.x];
        rowptr[i + 1] = val;
        if (i + 1 < N_NODES) cursor[i + 1] = val;
    }
    if (i == 0) { rowptr[0] = 0; cursor[0] = 0; }
}

__global__ __launch_bounds__(256) void scatter_kernel(const int* __restrict__ src,
                                                      const int* __restrict__ dst,
                                                      int* __restrict__ cursor,
                                                      int* __restrict__ col) {
    int e = blockIdx.x * 256 + threadIdx.x;   // grid exact
    int d = dst[e];
    int pos = atomicAdd(&cursor[d], 1);
    col[pos] = src[e];
}

// ---------------- pad W heads into Wp[64][224] (fp32, aligned) ----------------
__global__ __launch_bounds__(256) void wpad_kernel(const float* __restrict__ Wb,
                                                   const float* __restrict__ Ws,
                                                   float* __restrict__ Wp) {
    int i = blockIdx.x * 256 + threadIdx.x;
    if (i < 64 * LGJ) {
        int k = i / LGJ, j = i - k * LGJ;
        float w = 0.f;
        if (j < NB) w = Wb[k * NB + j];
        else if (j >= 112 && j < 112 + NB) w = Ws[k * NB + (j - 112)];
        Wp[i] = w;
    }
}

// ---------------- xws1 = ([x, stem] @ W1) * dis  (K=15) ----------------
__global__ __launch_bounds__(256) void xw1_kernel(const float* __restrict__ x,
                                                  const float* __restrict__ stem01,
                                                  const float* __restrict__ dis,
                                                  const float* __restrict__ W1,
                                                  float* __restrict__ xws) {
    __shared__ __align__(16) float W1s[15 * 64];
    __shared__ __align__(16) float xs[4][16];
    int tid = threadIdx.x;
    for (int i = tid; i < 960; i += 256) W1s[i] = W1[i];
    int n0 = blockIdx.x * 4;                     // grid exact: 25000*4 = 100000
    if (tid < 60) {
        int r = tid / 15, k = tid % 15;
        int n = n0 + r;
        xs[r][k] = (k < FIN) ? x[n * FIN + k] : stem01[n];
    }
    __syncthreads();
    int r = tid >> 6, f = tid & 63;
    float acc = 0.f;
#pragma unroll
    for (int k = 0; k < 15; k++) acc += xs[r][k] * W1s[k * 64 + f];
    xws[(n0 + r) * 64 + f] = acc * dis[n0 + r];
}

// ---------------- CSR aggregation + fused epilogue ----------------
__global__ __launch_bounds__(256) void agg_csr_kernel(const float* __restrict__ xws,
                                                      const int* __restrict__ rowptr,
                                                      const int* __restrict__ col,
                                                      const float* __restrict__ dis,
                                                      const float* __restrict__ bias,
                                                      const float* __restrict__ drop,
                                                      float* __restrict__ hout) {
    int node = (blockIdx.x * 256 + threadIdx.x) >> 6;  // grid exact: 25000*4
    int f = threadIdx.x & 63;
    int beg = rowptr[node], end = rowptr[node + 1];
    float acc0 = xws[node * 64 + f];   // self loop (already * dis[node])
    float acc1 = 0.f, acc2 = 0.f, acc3 = 0.f;
    int j = beg;
    for (; j + 4 <= end; j += 4) {
        int s0 = col[j], s1 = col[j + 1], s2 = col[j + 2], s3 = col[j + 3];
        acc0 += xws[s0 * 64 + f];
        acc1 += xws[s1 * 64 + f];
        acc2 += xws[s2 * 64 + f];
        acc3 += xws[s3 * 64 + f];
    }
    for (; j < end; j++) acc0 += xws[col[j] * 64 + f];
    float acc = (acc0 + acc1) + (acc2 + acc3);
    float r = fmaxf(fmaf(dis[node], acc, bias[f]), 0.f) * drop[node * 64 + f];
    hout[node * 64 + f] = r;
}

// ---------------- xws2 = (h1 @ W2) * dis  (64x64), in-place safe -------------
__global__ __launch_bounds__(256) void xw2_kernel(const float* __restrict__ h,
                                                  const float* __restrict__ dis,
                                                  const float* __restrict__ W2,
                                                  float* __restrict__ xws) {
    __shared__ __align__(16) float W2s[64 * 64];     // 16 KB
    __shared__ __align__(16) float hsT[64 * 68];     // k-major, pad 68: 17 KB
    int tid = threadIdx.x;
    for (int i = tid; i < 4096; i += 256) W2s[i] = W2[i];
    int n0 = blockIdx.x * 64;                        // grid 1563, tail guarded
    for (int i = tid; i < 4096; i += 256) {
        int m = i >> 6, k = i & 63;
        int n = n0 + m;
        hsT[k * 68 + m] = (n < N_NODES) ? h[n * 64 + k] : 0.f;
    }
    __syncthreads();
    int fg = tid & 15, mg = tid >> 4;
    int f0 = fg * 4, m0 = mg * 4;
    float acc[4][4];
#pragma unroll
    for (int i = 0; i < 4; i++)
#pragma unroll
        for (int j = 0; j < 4; j++) acc[i][j] = 0.f;
    for (int k = 0; k < 64; k++) {
        float4 w = *(const float4*)&W2s[k * 64 + f0];
        float4 hv = *(const float4*)&hsT[k * 68 + m0];
        float hh[4] = {hv.x, hv.y, hv.z, hv.w};
#pragma unroll
        for (int i = 0; i < 4; i++) {
            acc[i][0] += hh[i] * w.x;
            acc[i][1] += hh[i] * w.y;
            acc[i][2] += hh[i] * w.z;
            acc[i][3] += hh[i] * w.w;
        }
    }
#pragma unroll
    for (int i = 0; i < 4; i++) {
        int n = n0 + m0 + i;
        if (n < N_NODES) {
            float ds = dis[n];
            float4 r = make_float4(acc[i][0] * ds, acc[i][1] * ds,
                                   acc[i][2] * ds, acc[i][3] * ds);
            *(float4*)&xws[n * 64 + f0] = r;
        }
    }
}

// ---------------- fused head v2: W from L2, tiny LDS, chunked softmax --------
// M=64 nodes/block. Thread (tj,tm) = (tid%28, tid/28), tid<224: 8j x 8m tile.
// W read straight from L2 (Wp is 56 KB, resident). LDS: hT[64][68] fp32
// (17.4 KB) unioned with Lg[16][232] for softmax chunks.
__global__ __launch_bounds__(256) void head_kernel(const float* __restrict__ h2,
                                                   const float* __restrict__ Wp,
                                                   const float* __restrict__ bb,
                                                   const float* __restrict__ bs,
                                                   const float* __restrict__ gb,
                                                   const float* __restrict__ gs,
                                                   float* __restrict__ out) {
    __shared__ __align__(16) float smem[64 * 68];   // 17408 B; Lg needs 14848 B
    int tid = threadIdx.x;
    int n0 = blockIdx.x * HM;                       // grid 1563, tail guarded

    // stage h2 tile transposed -> hT[k][68] (coalesced global read)
    {
        const float4* src = (const float4*)(h2 + (size_t)n0 * 64);
#pragma unroll
        for (int q = 0; q < 4; q++) {
            int f4 = tid + q * 256;          // float4 index in tile, 0..1023
            int m = f4 >> 4;                 // 16 quads per 64-float row
            int k0 = (f4 & 15) * 4;
            float4 v = make_float4(0.f, 0.f, 0.f, 0.f);
            if (n0 + m < N_NODES) v = src[f4];
            smem[(k0 + 0) * 68 + m] = v.x;
            smem[(k0 + 1) * 68 + m] = v.y;
            smem[(k0 + 2) * 68 + m] = v.z;
            smem[(k0 + 3) * 68 + m] = v.w;
        }
    }
    __syncthreads();

    int tj = tid % 28, tm = tid / 28;
    bool act = tid < 224;
    int j0 = tj * 8, m0 = tm * 8;
    float acc[8][8];
#pragma unroll
    for (int a = 0; a < 8; a++)
#pragma unroll
        for (int b = 0; b < 8; b++) acc[a][b] = 0.f;

    if (act) {
        const float* wbase = Wp + j0;
#pragma unroll 2
        for (int k = 0; k < 64; k++) {
            float4 wa = *(const float4*)&wbase[k * LGJ];
            float4 wb2 = *(const float4*)&wbase[k * LGJ + 4];
            float4 h0 = *(const float4*)&smem[k * 68 + m0];
            float4 h1 = *(const float4*)&smem[k * 68 + m0 + 4];
            float wv[8] = {wa.x, wa.y, wa.z, wa.w, wb2.x, wb2.y, wb2.z, wb2.w};
            float hh[8] = {h0.x, h0.y, h0.z, h0.w, h1.x, h1.y, h1.z, h1.w};
#pragma unroll
            for (int a = 0; a < 8; a++)
#pragma unroll
                for (int b = 0; b < 8; b++) acc[a][b] += hh[a] * wv[b];
        }
    }

    // chunked: 4 chunks of 16 m; logits round-trip through LDS (reuse smem)
    int lane = tid & 31, grp = tid >> 5;
    for (int c = 0; c < 4; c++) {
        __syncthreads();   // hT / previous Lg no longer in use
        if (act && (tm >> 1) == c) {
            int lmBase = m0 - c * 16;      // 0 or 8
#pragma unroll
            for (int a = 0; a < 8; a++) {
                int lm = lmBase + a;
                *(float4*)&smem[lm * LGS + j0] =
                    make_float4(acc[a][0], acc[a][1], acc[a][2], acc[a][3]);
                *(float4*)&smem[lm * LGS + j0 + 4] =
                    make_float4(acc[a][4], acc[a][5], acc[a][6], acc[a][7]);
            }
        }
        __syncthreads();
#pragma unroll
        for (int pass = 0; pass < 4; pass++) {
            int p = grp + 8 * pass;        // 0..31
            int lm = p >> 1, head = p & 1;
            int n = n0 + c * 16 + lm;
            if (n >= N_NODES) continue;
            const float* bias = head ? bs : bb;
            const float* gum = head ? gs : gb;
            int jbase = head ? 112 : 0;
            float lg[4], z[4], e[4];
            float mx = -INFINITY;
#pragma unroll
            for (int i = 0; i < 4; i++) {
                int cc = lane + 32 * i;
                if (cc < NB) {
                    lg[i] = smem[lm * LGS + jbase + cc] + bias[cc];
                    z[i] = lg[i] + gum[(size_t)n * NB + cc];
                } else {
                    lg[i] = 0.f;
                    z[i] = -INFINITY;
                }
                mx = fmaxf(mx, z[i]);
            }
#pragma unroll
            for (int off = 16; off; off >>= 1) mx = fmaxf(mx, __shfl_xor(mx, off));
            float s = 0.f;
#pragma unroll
            for (int i = 0; i < 4; i++) {
                int cc = lane + 32 * i;
                e[i] = (cc < NB) ? __expf(z[i] - mx) : 0.f;
                s += e[i];
            }
#pragma unroll
            for (int off = 16; off; off >>= 1) s += __shfl_xor(s, off);
            float inv = 1.f / s;
            float* lo = out + (size_t)head * (N_NODES * NB) + (size_t)n * NB;
            float* so = out + (size_t)(2 + head) * (N_NODES * NB) + (size_t)n * NB;
#pragma unroll
            for (int i = 0; i < 4; i++) {
                int cc = lane + 32 * i;
                if (cc < NB) {
                    lo[cc] = lg[i];
                    so[cc] = e[i] * inv;
                }
            }
        }
    }
}

extern "C" void kernel_launch(void* const* d_in, const int* in_sizes, int n_in,
                              void* d_out, int out_size, void* d_ws, size_t ws_size,
                              hipStream_t stream) {
    const float* x     = (const float*)d_in[0];
    const float* W1    = (const float*)d_in[1];
    const float* b1    = (const float*)d_in[2];
    const float* W2    = (const float*)d_in[3];
    const float* b2    = (const float*)d_in[4];
    const float* Wb    = (const float*)d_in[5];
    const float* bb    = (const float*)d_in[6];
    const float* Ws    = (const float*)d_in[7];
    const float* bs    = (const float*)d_in[8];
    const float* drop1 = (const float*)d_in[9];
    const float* drop2 = (const float*)d_in[10];
    const float* gb    = (const float*)d_in[11];
    const float* gs    = (const float*)d_in[12];
    const int* edge    = (const int*)d_in[13];   // [2, E]
    const int* stem    = (const int*)d_in[14];   // [S]
    float* out = (float*)d_out;

    // workspace (4-byte elems):
    // A[N*64] | B[N*64] | dis[N] | stem01[N] | deg[N] | rowptr[N+1] |
    // cursor[N] | bsum | boff | col[E] | Wp[64*224]
    float* A      = (float*)d_ws;
    float* B      = A + (size_t)N_NODES * 64;
    float* dis    = B + (size_t)N_NODES * 64;
    float* stem01 = dis + N_NODES;
    int*   deg    = (int*)(stem01 + N_NODES);
    int*   rowptr = deg + N_NODES;
    int*   cursor = rowptr + (N_NODES + 1);
    int*   bsum   = cursor + N_NODES;
    int*   boff   = bsum + SCAN_BLOCKS;
    int*   col    = boff + SCAN_BLOCKS;
    float* Wp     = (float*)(col + N_EDGES);

    const int* esrc = edge;
    const int* edst = edge + N_EDGES;

    hipMemsetAsync(deg, 0, N_NODES * sizeof(int), stream);
    hipMemsetAsync(stem01, 0, N_NODES * sizeof(float), stream);

    deg_kernel<<<N_EDGES / 256, 256, 0, stream>>>(edst, deg);
    stem_kernel<<<(S_CNT + 255) / 256, 256, 0, stream>>>(stem, stem01);
    dis_kernel<<<SCAN_BLOCKS, 256, 0, stream>>>(deg, dis);
    wpad_kernel<<<(64 * LGJ + 255) / 256, 256, 0, stream>>>(Wb, Ws, Wp);

    // CSR build
    scan1_kernel<<<SCAN_BLOCKS, 256, 0, stream>>>(deg, rowptr, bsum);
    scan2_kernel<<<1, 512, 0, stream>>>(bsum, boff);
    scan3_kernel<<<SCAN_BLOCKS, 256, 0, stream>>>(boff, rowptr, cursor);
    scatter_kernel<<<N_EDGES / 256, 256, 0, stream>>>(esrc, edst, cursor, col);

    // layer 1: xws1 -> A; h1 -> B
    xw1_kernel<<<N_NODES / 4, 256, 0, stream>>>(x, stem01, dis, W1, A);
    agg_csr_kernel<<<(N_NODES * 64) / 256, 256, 0, stream>>>(A, rowptr, col, dis, b1, drop1, B);

    // layer 2: xws2 -> B (in-place over h1); h2 -> A
    xw2_kernel<<<(N_NODES + 63) / 64, 256, 0, stream>>>(B, dis, W2, B);
    agg_csr_kernel<<<(N_NODES * 64) / 256, 256, 0, stream>>>(B, rowptr, col, dis, b2, drop2, A);

    // fused heads: logits + gumbel softmax -> all 4 output sections
    head_kernel<<<(N_NODES + HM - 1) / HM, 256, 0, stream>>>(A, Wp, bb, bs, gb, gs, out);
}